// Round 1
// baseline (969.961 us; speedup 1.0000x reference)
//
#include <hip/hip_runtime.h>
#include <cmath>

#define BB 32     // batch
#define NN 784    // full points (28*28)
#define MM 392    // downsampled points (::2)
#define DD 1024   // feature dim
#define CC 20     // classes
#define JJ 3      // k-means centroids per class (K-1)
#define KP 4      // protos per class (3 centroids + backbone)
#define KM_ITERS 10

// ---------- cls_assign = argmax(score[:, ::2, :]), sm = mean, cnt via int atomics ----------
__global__ void k_cls(const float* __restrict__ score, int* __restrict__ cls,
                      float* __restrict__ sm, int* __restrict__ cnt) {
  int t = blockIdx.x * blockDim.x + threadIdx.x;
  if (t >= BB * MM) return;
  int b = t / MM, i = t - b * MM;
  const float* s = score + ((size_t)b * NN + 2 * i) * CC;
  float best = s[0]; int bi = 0; float acc = s[0];
  #pragma unroll
  for (int c = 1; c < CC; c++) { float v = s[c]; acc += v; if (v > best) { best = v; bi = c; } }
  cls[t] = bi;
  sm[t] = acc / (float)CC;
  atomicAdd(&cnt[b * CC + bi], 1);
}

// ---------- initial centroids: first 3 member indices (then earliest non-members) ----------
__global__ void k_init(const float* __restrict__ query, const int* __restrict__ cls,
                       float* __restrict__ cen) {
  int bc = blockIdx.x; int b = bc / CC, c = bc - b * CC;
  __shared__ int idx[JJ];
  if (threadIdx.x == 0) {
    int got = 0;
    for (int i = 0; i < MM && got < JJ; i++) if (cls[b * MM + i] == c) idx[got++] = i;
    for (int i = 0; i < MM && got < JJ; i++) if (cls[b * MM + i] != c) idx[got++] = i;
  }
  __syncthreads();
  for (int j = 0; j < JJ; j++) {
    const float* src = query + ((size_t)b * NN + 2 * idx[j]) * DD;
    float* dst = cen + ((size_t)bc * JJ + j) * DD;
    for (int k = threadIdx.x; k < DD; k += blockDim.x) dst[k] = src[k];
  }
}

// ---------- cen2 = sum(cen^2) per (b,c,j), one wave per row ----------
__global__ void k_cen2(const float* __restrict__ cen, float* __restrict__ cen2) {
  int id = blockIdx.x;
  const float* p = cen + (size_t)id * DD;
  float ss = 0.f;
  for (int k = threadIdx.x; k < DD; k += 64) { float v = p[k]; ss += v * v; }
  for (int o = 32; o > 0; o >>= 1) ss += __shfl_down(ss, o, 64);
  if (threadIdx.x == 0) cen2[id] = ss;
}

// ---------- assignment: each point vs its own class's 3 centroids; one wave per point ----------
__global__ __launch_bounds__(256) void k_assign(const float* __restrict__ query,
    const float* __restrict__ cen, const float* __restrict__ cen2,
    const int* __restrict__ cls, int* __restrict__ asg) {
  int wid = (blockIdx.x * blockDim.x + threadIdx.x) >> 6;
  int lane = threadIdx.x & 63;
  if (wid >= BB * MM) return;
  int b = wid / MM, i = wid - b * MM;
  int c = cls[wid];
  const float4* q4 = (const float4*)(query + ((size_t)b * NN + 2 * i) * DD);
  size_t cenoff = ((size_t)(b * CC + c)) * JJ * DD;
  const float4* c40 = (const float4*)(cen + cenoff);
  const float4* c41 = (const float4*)(cen + cenoff + DD);
  const float4* c42 = (const float4*)(cen + cenoff + 2 * DD);
  float d0 = 0.f, d1 = 0.f, d2 = 0.f, x2 = 0.f;
  #pragma unroll
  for (int u = 0; u < 4; u++) {
    float4 a  = q4[lane + 64 * u];
    float4 v0 = c40[lane + 64 * u];
    float4 v1 = c41[lane + 64 * u];
    float4 v2 = c42[lane + 64 * u];
    x2 += a.x * a.x + a.y * a.y + a.z * a.z + a.w * a.w;
    d0 += a.x * v0.x + a.y * v0.y + a.z * v0.z + a.w * v0.w;
    d1 += a.x * v1.x + a.y * v1.y + a.z * v1.z + a.w * v1.w;
    d2 += a.x * v2.x + a.y * v2.y + a.z * v2.z + a.w * v2.w;
  }
  for (int o = 32; o > 0; o >>= 1) {
    x2 += __shfl_down(x2, o, 64);
    d0 += __shfl_down(d0, o, 64);
    d1 += __shfl_down(d1, o, 64);
    d2 += __shfl_down(d2, o, 64);
  }
  if (lane == 0) {
    int base = (b * CC + c) * JJ;
    float e0 = (x2 - 2.f * d0) + cen2[base + 0];
    float e1 = (x2 - 2.f * d1) + cen2[base + 1];
    float e2 = (x2 - 2.f * d2) + cen2[base + 2];
    int bj = 0; float bv = e0;
    if (e1 < bv) { bv = e1; bj = 1; }
    if (e2 < bv) { bv = e2; bj = 2; }
    asg[wid] = bj;
  }
}

// ---------- centroid update: one block per (b,c,j), deterministic ascending-i sum ----------
__global__ __launch_bounds__(256) void k_upd(const float* __restrict__ query,
    const int* __restrict__ cls, const int* __restrict__ asg,
    float* __restrict__ cen, float* __restrict__ cen2) {
  int id = blockIdx.x;
  int j = id % JJ; int bc = id / JJ; int b = bc / CC; int c = bc - b * CC;
  const int* clsb = cls + b * MM;
  const int* asgb = asg + b * MM;
  int t = threadIdx.x;
  float4 acc = make_float4(0.f, 0.f, 0.f, 0.f);
  int count = 0;
  for (int i = 0; i < MM; i++) {
    if (clsb[i] == c && asgb[i] == j) {   // wave-uniform branch
      count++;
      float4 v = ((const float4*)(query + ((size_t)b * NN + 2 * i) * DD))[t];
      acc.x += v.x; acc.y += v.y; acc.z += v.z; acc.w += v.w;
    }
  }
  float* cp = cen + (size_t)id * DD;
  float4 vo;
  if (count > 0) {
    float kc = (float)count;
    vo = make_float4(acc.x / kc, acc.y / kc, acc.z / kc, acc.w / kc);
  } else {
    vo = ((const float4*)cp)[t];
  }
  ((float4*)cp)[t] = vo;
  float ss = vo.x * vo.x + vo.y * vo.y + vo.z * vo.z + vo.w * vo.w;
  __shared__ float red[256];
  red[t] = ss; __syncthreads();
  for (int o = 128; o > 0; o >>= 1) { if (t < o) red[t] += red[t + o]; __syncthreads(); }
  if (t == 0) cen2[id] = red[0];
}

// ---------- class sums (for backbone): one block per (b,c) ----------
__global__ __launch_bounds__(256) void k_classsum(const float* __restrict__ query,
    const int* __restrict__ cls, float* __restrict__ classsum) {
  int bc = blockIdx.x; int b = bc / CC; int c = bc - b * CC;
  const int* clsb = cls + b * MM;
  int t = threadIdx.x;
  float4 acc = make_float4(0.f, 0.f, 0.f, 0.f);
  for (int i = 0; i < MM; i++) {
    if (clsb[i] == c) {
      float4 v = ((const float4*)(query + ((size_t)b * NN + 2 * i) * DD))[t];
      acc.x += v.x; acc.y += v.y; acc.z += v.z; acc.w += v.w;
    }
  }
  ((float4*)(classsum + (size_t)bc * DD))[t] = acc;
}

__global__ void k_totalsum(const float* __restrict__ classsum, float* __restrict__ totalsum) {
  int t = blockIdx.x * 256 + threadIdx.x;   // over BB*DD
  int b = t / DD, k = t - b * DD;
  float s = 0.f;
  for (int c = 0; c < CC; c++) s += classsum[((size_t)b * CC + c) * DD + k];
  totalsum[t] = s;
}

// ---------- protos: avg-sort centroids, backbone, L2-normalize -> ph ----------
__global__ __launch_bounds__(256) void k_protos(const float* __restrict__ cen,
    const int* __restrict__ cls, const int* __restrict__ asg, const float* __restrict__ sm,
    const float* __restrict__ classsum, const float* __restrict__ totalsum,
    const int* __restrict__ cnt, float* __restrict__ ph) {
  int bc = blockIdx.x; int b = bc / CC; int c = bc - b * CC;
  __shared__ int ord[JJ];
  __shared__ float red[256];
  __shared__ float s_nrm;
  if (threadIdx.x == 0) {
    // deterministic ascending-i scan for kcnt / avg-sum (matches einsum order)
    int kc[JJ] = {0, 0, 0}; float av[JJ] = {0.f, 0.f, 0.f};
    const int* clsb = cls + b * MM; const int* asgb = asg + b * MM;
    const float* smb = sm + b * MM;
    for (int i = 0; i < MM; i++)
      if (clsb[i] == c) { int j = asgb[i]; kc[j]++; av[j] += smb[i]; }
    float avg[JJ];
    for (int j = 0; j < JJ; j++) avg[j] = (kc[j] > 0) ? (av[j] / (float)kc[j]) : -INFINITY;
    bool used[JJ] = {false, false, false};
    for (int s = 0; s < JJ; s++) {      // stable argsort descending
      int bi = -1; float bv = 0.f;
      for (int j = 0; j < JJ; j++) if (!used[j] && (bi < 0 || avg[j] > bv)) { bi = j; bv = avg[j]; }
      used[bi] = true; ord[s] = bi;
    }
  }
  __syncthreads();
  float denom = fmaxf((float)(MM - cnt[bc]), 1.f);
  for (int jj = 0; jj < KP; jj++) {
    float part = 0.f;
    for (int k = threadIdx.x; k < DD; k += 256) {
      float v;
      if (jj < JJ) v = cen[((size_t)bc * JJ + ord[jj]) * DD + k];
      else v = (totalsum[(size_t)b * DD + k] - classsum[(size_t)bc * DD + k]) / denom;
      part += v * v;
    }
    red[threadIdx.x] = part; __syncthreads();
    for (int o = 128; o > 0; o >>= 1) {
      if (threadIdx.x < o) red[threadIdx.x] += red[threadIdx.x + o];
      __syncthreads();
    }
    if (threadIdx.x == 0) s_nrm = fmaxf(sqrtf(red[0]), 1e-12f);
    __syncthreads();
    float nrm = s_nrm;
    for (int k = threadIdx.x; k < DD; k += 256) {
      float v;
      if (jj < JJ) v = cen[((size_t)bc * JJ + ord[jj]) * DD + k];
      else v = (totalsum[(size_t)b * DD + k] - classsum[(size_t)bc * DD + k]) / denom;
      ph[((size_t)bc * KP + jj) * DD + k] = v / nrm;
    }
    __syncthreads();
  }
}

// ---------- q0h = normalize(query[0]) rows; one wave per row ----------
__global__ void k_q0h(const float* __restrict__ query, float* __restrict__ q0h) {
  int n = blockIdx.x;
  const float* src = query + (size_t)n * DD;
  float ss = 0.f;
  for (int k = threadIdx.x; k < DD; k += 64) { float v = src[k]; ss += v * v; }
  for (int o = 32; o > 0; o >>= 1) ss += __shfl_xor(ss, o, 64);
  float nrm = fmaxf(sqrtf(ss), 1e-12f);
  for (int k = threadIdx.x; k < DD; k += 64) q0h[(size_t)n * DD + k] = src[k] / nrm;
}

// ---------- sim GEMM: Km[b,c,n,j] = exp(-(1-q0h[n]·ph[b,c,j])/0.1) ----------
// A = q0h (784 x 1024), B = ph (2560 x 1024), both K-major. 64x64 tile, 4x4 micro.
__global__ __launch_bounds__(256) void k_gemm(const float* __restrict__ A,
    const float* __restrict__ Bm, float* __restrict__ Km) {
  __shared__ float As[64][17];
  __shared__ float Bs[64][17];
  int tx = threadIdx.x & 15, ty = threadIdx.x >> 4;
  int m0 = blockIdx.x * 64, n0 = blockIdx.y * 64;
  int lrow = threadIdx.x >> 2;
  int lk = (threadIdx.x & 3) * 4;
  float acc[4][4] = {};
  for (int k0 = 0; k0 < DD; k0 += 16) {
    int ar = m0 + lrow;
    float4 av = (ar < NN) ? *(const float4*)(A + (size_t)ar * DD + k0 + lk)
                          : make_float4(0.f, 0.f, 0.f, 0.f);
    As[lrow][lk] = av.x; As[lrow][lk + 1] = av.y; As[lrow][lk + 2] = av.z; As[lrow][lk + 3] = av.w;
    float4 bv = *(const float4*)(Bm + (size_t)(n0 + lrow) * DD + k0 + lk);
    Bs[lrow][lk] = bv.x; Bs[lrow][lk + 1] = bv.y; Bs[lrow][lk + 2] = bv.z; Bs[lrow][lk + 3] = bv.w;
    __syncthreads();
    #pragma unroll
    for (int kk = 0; kk < 16; kk++) {
      float a[4], bb[4];
      #pragma unroll
      for (int i = 0; i < 4; i++) a[i] = As[ty * 4 + i][kk];
      #pragma unroll
      for (int j = 0; j < 4; j++) bb[j] = Bs[tx * 4 + j][kk];
      #pragma unroll
      for (int i = 0; i < 4; i++)
        #pragma unroll
        for (int j = 0; j < 4; j++) acc[i][j] += a[i] * bb[j];
    }
    __syncthreads();
  }
  #pragma unroll
  for (int i = 0; i < 4; i++) {
    int mr = m0 + ty * 4 + i;
    if (mr >= NN) continue;
    #pragma unroll
    for (int j = 0; j < 4; j++) {
      int q = n0 + tx * 4 + j;
      float sim = acc[i][j];
      Km[(size_t)(q >> 2) * ((size_t)NN * KP) + (size_t)mr * KP + (q & 3)] =
          expf(-(1.0f - sim) / 0.1f);
    }
  }
}

// ---------- Sinkhorn + BCE per (b,c); Km tile resident in LDS ----------
__global__ __launch_bounds__(256) void k_sink(const float* __restrict__ Km,
    const int* __restrict__ label, const int* __restrict__ cnt,
    const int* __restrict__ gt, const float* __restrict__ wts,
    float* __restrict__ bce, int* __restrict__ vld) {
  int bc = blockIdx.x; int b = bc / CC, c = bc - b * CC;
  if (label[bc] <= 0 || cnt[bc] < KP) {     // uniform early-out: invalid pair
    if (threadIdx.x == 0) { bce[bc] = 0.f; vld[bc] = 0; }
    return;
  }
  __shared__ __align__(16) float4 Ks[NN];   // 12.5 KB
  __shared__ float r[NN];
  __shared__ float ccv[KP];
  __shared__ float wred[4][5];
  __shared__ float s_err;
  __shared__ int s_nan;
  const float4* Kg = (const float4*)(Km + (size_t)bc * NN * KP);
  for (int t = threadIdx.x; t < NN; t += 256) { Ks[t] = Kg[t]; r[t] = 1.f; }
  if (threadIdx.x < KP) ccv[threadIdx.x] = 1.f;
  if (threadIdx.x == 0) s_nan = 0;
  __syncthreads();
  const float uu = 1.0f / (float)NN, vv = 1.0f / (float)KP;
  int lane = threadIdx.x & 63, wv = threadIdx.x >> 6;
  for (int it = 0; it < 100; it++) {
    float c0 = ccv[0], c1 = ccv[1], c2 = ccv[2], c3 = ccv[3];
    float dsum = 0.f, p0 = 0.f, p1 = 0.f, p2 = 0.f, p3 = 0.f;
    for (int n = threadIdx.x; n < NN; n += 256) {
      float4 kv = Ks[n];
      float S = kv.x * c0 + kv.y * c1 + kv.z * c2 + kv.w * c3;
      float r1 = uu / S;
      dsum += fabsf(r1 - r[n]);
      r[n] = r1;
      p0 += kv.x * r1; p1 += kv.y * r1; p2 += kv.z * r1; p3 += kv.w * r1;
    }
    for (int o = 32; o > 0; o >>= 1) {
      dsum += __shfl_down(dsum, o, 64);
      p0 += __shfl_down(p0, o, 64); p1 += __shfl_down(p1, o, 64);
      p2 += __shfl_down(p2, o, 64); p3 += __shfl_down(p3, o, 64);
    }
    if (lane == 0) { wred[wv][0] = dsum; wred[wv][1] = p0; wred[wv][2] = p1; wred[wv][3] = p2; wred[wv][4] = p3; }
    __syncthreads();
    if (threadIdx.x == 0) {
      float d = 0.f, q0 = 0.f, q1 = 0.f, q2 = 0.f, q3 = 0.f;
      for (int w = 0; w < 4; w++) { d += wred[w][0]; q0 += wred[w][1]; q1 += wred[w][2]; q2 += wred[w][3]; q3 += wred[w][4]; }
      ccv[0] = vv / q0; ccv[1] = vv / q1; ccv[2] = vv / q2; ccv[3] = vv / q3;
      s_err = d / (float)NN;
    }
    __syncthreads();
    if (s_err < 0.01f) break;               // uniform
  }
  float w0 = wts[0], w1 = wts[1], w2 = wts[2], w3 = wts[3];
  float cc0 = ccv[0], cc1 = ccv[1], cc2 = ccv[2], cc3 = ccv[3];
  float bsum = 0.f; int nanloc = 0;
  const int* gtb = gt + b * NN;
  for (int n = threadIdx.x; n < NN; n += 256) {
    float4 kv = Ks[n];
    float rv = r[n];
    float T0 = rv * cc0 * kv.x, T1 = rv * cc1 * kv.y, T2 = rv * cc2 * kv.z, T3 = rv * cc3 * kv.w;
    if (T0 != T0 || T1 != T1 || T2 != T2 || T3 != T3) nanloc = 1;
    float pred = T0 * w0 + T1 * w1 + T2 * w2 + T3 * w3;
    float p = fminf(fmaxf(pred, 0.f), 1.f);
    float t = (gtb[n] == c + 1) ? fmaxf(logf(p), -100.f) : fmaxf(logf(1.f - p), -100.f);
    bsum += t;
  }
  if (nanloc) s_nan = 1;
  for (int o = 32; o > 0; o >>= 1) bsum += __shfl_down(bsum, o, 64);
  if (lane == 0) wred[wv][0] = bsum;
  __syncthreads();
  if (threadIdx.x == 0) {
    float tot = wred[0][0] + wred[1][0] + wred[2][0] + wred[3][0];
    if (s_nan) { bce[bc] = 0.f; vld[bc] = 0; }
    else { bce[bc] = -(tot / (float)NN); vld[bc] = 1; }
  }
}

// ---------- final scalar: sum(bce)/(num_valid + 1e-4) ----------
__global__ void k_final(const float* __restrict__ bce, const int* __restrict__ vld,
                        float* __restrict__ out) {
  __shared__ float rs[256];
  __shared__ float rc[256];
  float s = 0.f, cv = 0.f;
  for (int t = threadIdx.x; t < BB * CC; t += 256) { s += bce[t]; cv += (float)vld[t]; }
  rs[threadIdx.x] = s; rc[threadIdx.x] = cv; __syncthreads();
  for (int o = 128; o > 0; o >>= 1) {
    if (threadIdx.x < o) { rs[threadIdx.x] += rs[threadIdx.x + o]; rc[threadIdx.x] += rc[threadIdx.x + o]; }
    __syncthreads();
  }
  if (threadIdx.x == 0) out[0] = rs[0] / (rc[0] + 0.0001f);
}

extern "C" void kernel_launch(void* const* d_in, const int* in_sizes, int n_in,
                              void* d_out, int out_size, void* d_ws, size_t ws_size,
                              hipStream_t stream) {
  (void)in_sizes; (void)n_in; (void)out_size; (void)ws_size;
  const float* query = (const float*)d_in[0];
  const float* score = (const float*)d_in[1];
  const int*   label = (const int*)d_in[2];
  const int*   gt    = (const int*)d_in[3];
  const float* wts   = (const float*)d_in[4];
  float* ws = (float*)d_ws;

  size_t off = 0;
  int* cls = (int*)(ws + off);       off += (size_t)BB * MM;
  int* asg = (int*)(ws + off);       off += (size_t)BB * MM;
  int* cnt = (int*)(ws + off);       off += (size_t)BB * CC;
  float* sm = ws + off;              off += (size_t)BB * MM;
  float* classsum = ws + off;        off += (size_t)BB * CC * DD;
  float* totalsum = ws + off;        off += (size_t)BB * DD;
  float* cen = ws + off;             off += (size_t)BB * CC * JJ * DD;
  float* cen2 = ws + off;            off += (size_t)BB * CC * JJ;
  float* ph = ws + off;              off += (size_t)BB * CC * KP * DD;
  float* q0h = ws + off;             off += (size_t)NN * DD;
  float* Km = ws + off;              off += (size_t)BB * CC * NN * KP;
  float* bce = ws + off;             off += (size_t)BB * CC;
  int* vld = (int*)(ws + off);       off += (size_t)BB * CC;   // ~29 MB total

  hipMemsetAsync(cnt, 0, (size_t)BB * CC * sizeof(int), stream);
  k_cls<<<(BB * MM + 255) / 256, 256, 0, stream>>>(score, cls, sm, cnt);
  k_init<<<BB * CC, 256, 0, stream>>>(query, cls, cen);
  k_cen2<<<BB * CC * JJ, 64, 0, stream>>>(cen, cen2);
  k_classsum<<<BB * CC, 256, 0, stream>>>(query, cls, classsum);
  k_totalsum<<<(BB * DD) / 256, 256, 0, stream>>>(classsum, totalsum);
  for (int it = 0; it < KM_ITERS; it++) {
    k_assign<<<BB * MM / 4, 256, 0, stream>>>(query, cen, cen2, cls, asg);
    k_upd<<<BB * CC * JJ, 256, 0, stream>>>(query, cls, asg, cen, cen2);
  }
  k_assign<<<BB * MM / 4, 256, 0, stream>>>(query, cen, cen2, cls, asg);  // final assign
  k_protos<<<BB * CC, 256, 0, stream>>>(cen, cls, asg, sm, classsum, totalsum, cnt, ph);
  k_q0h<<<NN, 64, 0, stream>>>(query, q0h);
  dim3 gg((NN + 63) / 64, (BB * CC * KP) / 64);
  k_gemm<<<gg, 256, 0, stream>>>(q0h, ph, Km);
  k_sink<<<BB * CC, 256, 0, stream>>>(Km, label, cnt, gt, wts, bce, vld);
  k_final<<<1, 256, 0, stream>>>(bce, vld, (float*)d_out);
}

// Round 2
// 417.647 us; speedup vs baseline: 2.3224x; 2.3224x over previous
//
#include <hip/hip_runtime.h>
#include <cmath>

#define BB 32     // batch
#define NN 784    // full points (28*28)
#define MM 392    // downsampled points (::2)
#define DD 1024   // feature dim
#define CC 20     // classes
#define JJ 3      // k-means centroids per class (K-1)
#define KP 4      // protos per class (3 centroids + backbone)
#define KM_ITERS 10

// ---------- cls_assign = argmax(score[:, ::2, :]), sm = mean, cnt via int atomics ----------
__global__ void k_cls(const float* __restrict__ score, int* __restrict__ cls,
                      float* __restrict__ sm, int* __restrict__ cnt) {
  int t = blockIdx.x * blockDim.x + threadIdx.x;
  if (t >= BB * MM) return;
  int b = t / MM, i = t - b * MM;
  const float* s = score + ((size_t)b * NN + 2 * i) * CC;
  float best = s[0]; int bi = 0; float acc = s[0];
  #pragma unroll
  for (int c = 1; c < CC; c++) { float v = s[c]; acc += v; if (v > best) { best = v; bi = c; } }
  cls[t] = bi;
  sm[t] = acc / (float)CC;
  atomicAdd(&cnt[b * CC + bi], 1);
}

// ---------- fused k-means per (b,c): membership, init, 10 iters, final assign,
//            avg-sort, write normalized protos ph[0..2] + classsum ----------
#define CEN2_BLOCK() do {                                                     \
    float p0, p1, p2;                                                         \
    { float4 v = *(const float4*)&s_cen[0][tid * 4];                          \
      p0 = v.x * v.x + v.y * v.y + v.z * v.z + v.w * v.w; }                   \
    { float4 v = *(const float4*)&s_cen[1][tid * 4];                          \
      p1 = v.x * v.x + v.y * v.y + v.z * v.z + v.w * v.w; }                   \
    { float4 v = *(const float4*)&s_cen[2][tid * 4];                          \
      p2 = v.x * v.x + v.y * v.y + v.z * v.z + v.w * v.w; }                   \
    for (int o = 1; o < 64; o <<= 1) {                                        \
      p0 += __shfl_xor(p0, o, 64); p1 += __shfl_xor(p1, o, 64);               \
      p2 += __shfl_xor(p2, o, 64);                                            \
    }                                                                         \
    if (lane == 0) { s_red[wv][0] = p0; s_red[wv][1] = p1; s_red[wv][2] = p2; }\
    __syncthreads();                                                          \
    if (tid == 0) {                                                           \
      s_cen2[0] = s_red[0][0] + s_red[1][0] + s_red[2][0] + s_red[3][0];      \
      s_cen2[1] = s_red[0][1] + s_red[1][1] + s_red[2][1] + s_red[3][1];      \
      s_cen2[2] = s_red[0][2] + s_red[1][2] + s_red[2][2] + s_red[3][2];      \
    }                                                                         \
    __syncthreads();                                                          \
  } while (0)

__global__ __launch_bounds__(256) void k_kmeans(
    const float* __restrict__ query, const int* __restrict__ cls,
    const float* __restrict__ sm, const int* __restrict__ cnt,
    const int* __restrict__ label,
    float* __restrict__ ph, float* __restrict__ classsum) {
  int bc = blockIdx.x; int b = bc / CC, c = bc - b * CC;
  int tid = threadIdx.x, lane = tid & 63, wv = tid >> 6;

  __shared__ int s_cls[MM];
  __shared__ int s_list[MM];
  __shared__ float s_cen[JJ][DD];       // 12 KB
  __shared__ float s_part[4][JJ][DD];   // 48 KB
  __shared__ float s_cen2[JJ];
  __shared__ int s_kcnt[4][JJ];
  __shared__ float s_smv[4][JJ];
  __shared__ int s_memcnt;
  __shared__ int s_ord[JJ];
  __shared__ float s_red[4][4];
  __shared__ float s_bcast;

  for (int i = tid; i < MM; i += 256) s_cls[i] = cls[b * MM + i];
  __syncthreads();
  if (tid == 0) {
    int mc = 0;
    for (int i = 0; i < MM; i++) if (s_cls[i] == c) s_list[mc++] = i;
    s_memcnt = mc;
  }
  __syncthreads();
  int memcnt = s_memcnt;

  // ---- pass A: classsum = sum of member rows (needed for totalsum for ALL bc)
  {
    float4 a0 = make_float4(0.f, 0.f, 0.f, 0.f), a1 = a0, a2 = a0, a3 = a0;
    for (int g = wv; g < memcnt; g += 4) {
      const float* qr = query + ((size_t)b * NN + 2 * s_list[g]) * DD;
      float4 v0 = *(const float4*)(qr + lane * 4);
      float4 v1 = *(const float4*)(qr + lane * 4 + 256);
      float4 v2 = *(const float4*)(qr + lane * 4 + 512);
      float4 v3 = *(const float4*)(qr + lane * 4 + 768);
      a0.x += v0.x; a0.y += v0.y; a0.z += v0.z; a0.w += v0.w;
      a1.x += v1.x; a1.y += v1.y; a1.z += v1.z; a1.w += v1.w;
      a2.x += v2.x; a2.y += v2.y; a2.z += v2.z; a2.w += v2.w;
      a3.x += v3.x; a3.y += v3.y; a3.z += v3.z; a3.w += v3.w;
    }
    *(float4*)&s_part[wv][0][lane * 4]       = a0;
    *(float4*)&s_part[wv][0][lane * 4 + 256] = a1;
    *(float4*)&s_part[wv][0][lane * 4 + 512] = a2;
    *(float4*)&s_part[wv][0][lane * 4 + 768] = a3;
  }
  __syncthreads();
  for (int k = tid; k < DD; k += 256)
    classsum[(size_t)bc * DD + k] =
        s_part[0][0][k] + s_part[1][0][k] + s_part[2][0][k] + s_part[3][0][k];

  if (label[bc] <= 0 || memcnt < KP) return;   // invalid: protos never consumed

  // ---- init centroids = first JJ members (ascending), matches argsort order
  for (int j = 0; j < JJ; j++) {
    const float* qr = query + ((size_t)b * NN + 2 * s_list[j]) * DD;
    float4 v = *(const float4*)(qr + tid * 4);
    *(float4*)&s_cen[j][tid * 4] = v;
  }
  __syncthreads();

  for (int it = 0; it < KM_ITERS; it++) {
    CEN2_BLOCK();
    float4 A0[4], A1[4], A2[4];
    #pragma unroll
    for (int u = 0; u < 4; u++) {
      A0[u] = make_float4(0.f, 0.f, 0.f, 0.f); A1[u] = A0[u]; A2[u] = A0[u];
    }
    int c0 = 0, c1 = 0, c2 = 0;
    int g = wv;
    float4 q[4];
    if (g < memcnt) {
      const float* qr = query + ((size_t)b * NN + 2 * s_list[g]) * DD;
      #pragma unroll
      for (int u = 0; u < 4; u++) q[u] = *(const float4*)(qr + lane * 4 + u * 256);
    }
    while (g < memcnt) {
      int gn = g + 4;
      float4 qn[4];
      if (gn < memcnt) {
        const float* qr = query + ((size_t)b * NN + 2 * s_list[gn]) * DD;
        #pragma unroll
        for (int u = 0; u < 4; u++) qn[u] = *(const float4*)(qr + lane * 4 + u * 256);
      }
      float x2 = 0.f, d0 = 0.f, d1 = 0.f, d2 = 0.f;
      #pragma unroll
      for (int u = 0; u < 4; u++) {
        float4 qv = q[u];
        float4 v0 = *(const float4*)&s_cen[0][lane * 4 + u * 256];
        float4 v1 = *(const float4*)&s_cen[1][lane * 4 + u * 256];
        float4 v2 = *(const float4*)&s_cen[2][lane * 4 + u * 256];
        x2 += qv.x * qv.x + qv.y * qv.y + qv.z * qv.z + qv.w * qv.w;
        d0 += qv.x * v0.x + qv.y * v0.y + qv.z * v0.z + qv.w * v0.w;
        d1 += qv.x * v1.x + qv.y * v1.y + qv.z * v1.z + qv.w * v1.w;
        d2 += qv.x * v2.x + qv.y * v2.y + qv.z * v2.z + qv.w * v2.w;
      }
      for (int o = 1; o < 64; o <<= 1) {
        x2 += __shfl_xor(x2, o, 64); d0 += __shfl_xor(d0, o, 64);
        d1 += __shfl_xor(d1, o, 64); d2 += __shfl_xor(d2, o, 64);
      }
      float e0 = (x2 - 2.f * d0) + s_cen2[0];
      float e1 = (x2 - 2.f * d1) + s_cen2[1];
      float e2 = (x2 - 2.f * d2) + s_cen2[2];
      int bj = 0; float bv = e0;
      if (e1 < bv) { bv = e1; bj = 1; }
      if (e2 < bv) { bv = e2; bj = 2; }
      if (bj == 0) {
        #pragma unroll
        for (int u = 0; u < 4; u++) { A0[u].x += q[u].x; A0[u].y += q[u].y; A0[u].z += q[u].z; A0[u].w += q[u].w; }
        c0++;
      } else if (bj == 1) {
        #pragma unroll
        for (int u = 0; u < 4; u++) { A1[u].x += q[u].x; A1[u].y += q[u].y; A1[u].z += q[u].z; A1[u].w += q[u].w; }
        c1++;
      } else {
        #pragma unroll
        for (int u = 0; u < 4; u++) { A2[u].x += q[u].x; A2[u].y += q[u].y; A2[u].z += q[u].z; A2[u].w += q[u].w; }
        c2++;
      }
      #pragma unroll
      for (int u = 0; u < 4; u++) q[u] = qn[u];
      g = gn;
    }
    #pragma unroll
    for (int u = 0; u < 4; u++) {
      *(float4*)&s_part[wv][0][lane * 4 + u * 256] = A0[u];
      *(float4*)&s_part[wv][1][lane * 4 + u * 256] = A1[u];
      *(float4*)&s_part[wv][2][lane * 4 + u * 256] = A2[u];
    }
    if (lane == 0) { s_kcnt[wv][0] = c0; s_kcnt[wv][1] = c1; s_kcnt[wv][2] = c2; }
    __syncthreads();
    int kc0 = s_kcnt[0][0] + s_kcnt[1][0] + s_kcnt[2][0] + s_kcnt[3][0];
    int kc1 = s_kcnt[0][1] + s_kcnt[1][1] + s_kcnt[2][1] + s_kcnt[3][1];
    int kc2 = s_kcnt[0][2] + s_kcnt[1][2] + s_kcnt[2][2] + s_kcnt[3][2];
    for (int p = tid; p < JJ * DD; p += 256) {
      int j = p >> 10, k = p & (DD - 1);
      int kc = (j == 0) ? kc0 : (j == 1 ? kc1 : kc2);
      if (kc > 0) {
        float sv = s_part[0][j][k] + s_part[1][j][k] + s_part[2][j][k] + s_part[3][j][k];
        s_cen[j][k] = sv / (float)kc;
      }
    }
    __syncthreads();
  }

  // ---- final assignment: kcnt + sm-sum only (centroids not updated)
  CEN2_BLOCK();
  {
    int c0 = 0, c1 = 0, c2 = 0;
    float sm0 = 0.f, sm1 = 0.f, sm2 = 0.f;
    for (int g = wv; g < memcnt; g += 4) {
      const float* qr = query + ((size_t)b * NN + 2 * s_list[g]) * DD;
      float x2 = 0.f, d0 = 0.f, d1 = 0.f, d2 = 0.f;
      #pragma unroll
      for (int u = 0; u < 4; u++) {
        float4 qv = *(const float4*)(qr + lane * 4 + u * 256);
        float4 v0 = *(const float4*)&s_cen[0][lane * 4 + u * 256];
        float4 v1 = *(const float4*)&s_cen[1][lane * 4 + u * 256];
        float4 v2 = *(const float4*)&s_cen[2][lane * 4 + u * 256];
        x2 += qv.x * qv.x + qv.y * qv.y + qv.z * qv.z + qv.w * qv.w;
        d0 += qv.x * v0.x + qv.y * v0.y + qv.z * v0.z + qv.w * v0.w;
        d1 += qv.x * v1.x + qv.y * v1.y + qv.z * v1.z + qv.w * v1.w;
        d2 += qv.x * v2.x + qv.y * v2.y + qv.z * v2.z + qv.w * v2.w;
      }
      for (int o = 1; o < 64; o <<= 1) {
        x2 += __shfl_xor(x2, o, 64); d0 += __shfl_xor(d0, o, 64);
        d1 += __shfl_xor(d1, o, 64); d2 += __shfl_xor(d2, o, 64);
      }
      float e0 = (x2 - 2.f * d0) + s_cen2[0];
      float e1 = (x2 - 2.f * d1) + s_cen2[1];
      float e2 = (x2 - 2.f * d2) + s_cen2[2];
      int bj = 0; float bv = e0;
      if (e1 < bv) { bv = e1; bj = 1; }
      if (e2 < bv) { bv = e2; bj = 2; }
      float sv = sm[b * MM + s_list[g]];
      if (bj == 0) { c0++; sm0 += sv; }
      else if (bj == 1) { c1++; sm1 += sv; }
      else { c2++; sm2 += sv; }
    }
    if (lane == 0) {
      s_kcnt[wv][0] = c0; s_kcnt[wv][1] = c1; s_kcnt[wv][2] = c2;
      s_smv[wv][0] = sm0; s_smv[wv][1] = sm1; s_smv[wv][2] = sm2;
    }
  }
  __syncthreads();
  if (tid == 0) {
    float avg[JJ];
    for (int j = 0; j < JJ; j++) {
      int kc = s_kcnt[0][j] + s_kcnt[1][j] + s_kcnt[2][j] + s_kcnt[3][j];
      float ss = s_smv[0][j] + s_smv[1][j] + s_smv[2][j] + s_smv[3][j];
      avg[j] = (kc > 0) ? (ss / (float)kc) : -INFINITY;
    }
    bool used[JJ] = {false, false, false};
    for (int s = 0; s < JJ; s++) {       // stable argsort descending
      int bi = -1; float bv = 0.f;
      for (int j = 0; j < JJ; j++)
        if (!used[j] && (bi < 0 || avg[j] > bv)) { bi = j; bv = avg[j]; }
      used[bi] = true; s_ord[s] = bi;
    }
  }
  __syncthreads();
  // ---- normalize + write sorted centroids to ph
  for (int jj = 0; jj < JJ; jj++) {
    int j = s_ord[jj];
    float4 v = *(const float4*)&s_cen[j][tid * 4];
    float pp = v.x * v.x + v.y * v.y + v.z * v.z + v.w * v.w;
    for (int o = 1; o < 64; o <<= 1) pp += __shfl_xor(pp, o, 64);
    if (lane == 0) s_red[wv][0] = pp;
    __syncthreads();
    if (tid == 0)
      s_bcast = fmaxf(sqrtf(s_red[0][0] + s_red[1][0] + s_red[2][0] + s_red[3][0]), 1e-12f);
    __syncthreads();
    float nrm = s_bcast;
    float4 o4 = make_float4(v.x / nrm, v.y / nrm, v.z / nrm, v.w / nrm);
    *(float4*)(ph + ((size_t)bc * KP + jj) * DD + tid * 4) = o4;
    __syncthreads();
  }
}

// ---------- totalsum[b][k] = sum_c classsum[b][c][k] ----------
__global__ void k_totalsum(const float* __restrict__ classsum, float* __restrict__ totalsum) {
  int t = blockIdx.x * 256 + threadIdx.x;   // over BB*DD
  int b = t >> 10, k = t & (DD - 1);
  float s = 0.f;
  for (int c = 0; c < CC; c++) s += classsum[((size_t)b * CC + c) * DD + k];
  totalsum[t] = s;
}

// ---------- backbone proto (row 3 of ph), valid bc only ----------
__global__ __launch_bounds__(256) void k_backbone(const float* __restrict__ totalsum,
    const float* __restrict__ classsum, const int* __restrict__ cnt,
    const int* __restrict__ label, float* __restrict__ ph) {
  int bc = blockIdx.x; int b = bc / CC;
  if (label[bc] <= 0 || cnt[bc] < KP) return;
  int tid = threadIdx.x, lane = tid & 63, wv = tid >> 6;
  __shared__ float s_red[4];
  __shared__ float s_nrm;
  float denom = fmaxf((float)(MM - cnt[bc]), 1.f);
  float4 tv = *(const float4*)(totalsum + (size_t)b * DD + tid * 4);
  float4 cv = *(const float4*)(classsum + (size_t)bc * DD + tid * 4);
  float4 v = make_float4((tv.x - cv.x) / denom, (tv.y - cv.y) / denom,
                         (tv.z - cv.z) / denom, (tv.w - cv.w) / denom);
  float pp = v.x * v.x + v.y * v.y + v.z * v.z + v.w * v.w;
  for (int o = 1; o < 64; o <<= 1) pp += __shfl_xor(pp, o, 64);
  if (lane == 0) s_red[wv] = pp;
  __syncthreads();
  if (tid == 0) s_nrm = fmaxf(sqrtf(s_red[0] + s_red[1] + s_red[2] + s_red[3]), 1e-12f);
  __syncthreads();
  float nrm = s_nrm;
  *(float4*)(ph + ((size_t)bc * KP + 3) * DD + tid * 4) =
      make_float4(v.x / nrm, v.y / nrm, v.z / nrm, v.w / nrm);
}

// ---------- q0h = normalize(query[0]) rows; one wave per row ----------
__global__ void k_q0h(const float* __restrict__ query, float* __restrict__ q0h) {
  int n = blockIdx.x;
  const float* src = query + (size_t)n * DD;
  float ss = 0.f;
  for (int k = threadIdx.x; k < DD; k += 64) { float v = src[k]; ss += v * v; }
  for (int o = 32; o > 0; o >>= 1) ss += __shfl_xor(ss, o, 64);
  float nrm = fmaxf(sqrtf(ss), 1e-12f);
  for (int k = threadIdx.x; k < DD; k += 64) q0h[(size_t)n * DD + k] = src[k] / nrm;
}

// ---------- sim GEMM, split-K x2: P[s][m][n] = dot(q0h[m], ph[n]) over K-half s ----------
__global__ __launch_bounds__(256) void k_gemm(const float* __restrict__ A,
    const float* __restrict__ Bm, float* __restrict__ P) {
  __shared__ float As[64][20];
  __shared__ float Bs[64][20];
  int tx = threadIdx.x & 15, ty = threadIdx.x >> 4;
  int m0 = blockIdx.x * 64, n0 = blockIdx.y * 64;
  int s = blockIdx.z;
  int lrow = threadIdx.x >> 2;
  int lk = (threadIdx.x & 3) * 4;
  float acc[4][4] = {};
  int kbase = s * 512;
  for (int k0 = kbase; k0 < kbase + 512; k0 += 16) {
    int ar = m0 + lrow;
    float4 av = (ar < NN) ? *(const float4*)(A + (size_t)ar * DD + k0 + lk)
                          : make_float4(0.f, 0.f, 0.f, 0.f);
    *(float4*)&As[lrow][lk] = av;
    float4 bv = *(const float4*)(Bm + (size_t)(n0 + lrow) * DD + k0 + lk);
    *(float4*)&Bs[lrow][lk] = bv;
    __syncthreads();
    #pragma unroll
    for (int kk = 0; kk < 16; kk += 4) {
      float4 a4[4], b4[4];
      #pragma unroll
      for (int i = 0; i < 4; i++) a4[i] = *(const float4*)&As[ty * 4 + i][kk];
      #pragma unroll
      for (int j = 0; j < 4; j++) b4[j] = *(const float4*)&Bs[tx + 16 * j][kk];
      #pragma unroll
      for (int i = 0; i < 4; i++)
        #pragma unroll
        for (int j = 0; j < 4; j++) {
          acc[i][j] += a4[i].x * b4[j].x;
          acc[i][j] += a4[i].y * b4[j].y;
          acc[i][j] += a4[i].z * b4[j].z;
          acc[i][j] += a4[i].w * b4[j].w;
        }
    }
    __syncthreads();
  }
  #pragma unroll
  for (int i = 0; i < 4; i++) {
    int mr = m0 + ty * 4 + i;
    if (mr >= NN) continue;
    float* row = P + ((size_t)s * NN + mr) * (size_t)(BB * CC * KP) + n0 + tx;
    #pragma unroll
    for (int j = 0; j < 4; j++) row[16 * j] = acc[i][j];
  }
}

// ---------- reduce split-K + exp -> Km[bc][n][4] ----------
__global__ void k_kred(const float* __restrict__ P, float* __restrict__ Km) {
  int t = blockIdx.x * 256 + threadIdx.x;   // over NN * (BB*CC), bc fastest
  if (t >= NN * BB * CC) return;
  int m = t / (BB * CC);
  int bc = t - m * (BB * CC);
  const float4* p0 = (const float4*)(P + (size_t)m * (BB * CC * KP)) + bc;
  const float4* p1 = (const float4*)(P + ((size_t)NN + m) * (BB * CC * KP)) + bc;
  float4 a = *p0, bvv = *p1;
  float4 o;
  o.x = expf(-(1.0f - (a.x + bvv.x)) / 0.1f);
  o.y = expf(-(1.0f - (a.y + bvv.y)) / 0.1f);
  o.z = expf(-(1.0f - (a.z + bvv.z)) / 0.1f);
  o.w = expf(-(1.0f - (a.w + bvv.w)) / 0.1f);
  *((float4*)Km + (size_t)bc * NN + m) = o;
}

// ---------- Sinkhorn + BCE per (b,c); Km tile resident in LDS ----------
__global__ __launch_bounds__(256) void k_sink(const float* __restrict__ Km,
    const int* __restrict__ label, const int* __restrict__ cnt,
    const int* __restrict__ gt, const float* __restrict__ wts,
    float* __restrict__ bce, int* __restrict__ vld) {
  int bc = blockIdx.x; int b = bc / CC, c = bc - b * CC;
  if (label[bc] <= 0 || cnt[bc] < KP) {     // uniform early-out: invalid pair
    if (threadIdx.x == 0) { bce[bc] = 0.f; vld[bc] = 0; }
    return;
  }
  __shared__ __align__(16) float4 Ks[NN];   // 12.5 KB
  __shared__ float r[NN];
  __shared__ float ccv[KP];
  __shared__ float wred[4][5];
  __shared__ float s_err;
  __shared__ int s_nan;
  const float4* Kg = (const float4*)(Km + (size_t)bc * NN * KP);
  for (int t = threadIdx.x; t < NN; t += 256) { Ks[t] = Kg[t]; r[t] = 1.f; }
  if (threadIdx.x < KP) ccv[threadIdx.x] = 1.f;
  if (threadIdx.x == 0) s_nan = 0;
  __syncthreads();
  const float uu = 1.0f / (float)NN, vv = 1.0f / (float)KP;
  int lane = threadIdx.x & 63, wv = threadIdx.x >> 6;
  for (int it = 0; it < 100; it++) {
    float c0 = ccv[0], c1 = ccv[1], c2 = ccv[2], c3 = ccv[3];
    float dsum = 0.f, p0 = 0.f, p1 = 0.f, p2 = 0.f, p3 = 0.f;
    for (int n = threadIdx.x; n < NN; n += 256) {
      float4 kv = Ks[n];
      float S = kv.x * c0 + kv.y * c1 + kv.z * c2 + kv.w * c3;
      float r1 = uu / S;
      dsum += fabsf(r1 - r[n]);
      r[n] = r1;
      p0 += kv.x * r1; p1 += kv.y * r1; p2 += kv.z * r1; p3 += kv.w * r1;
    }
    for (int o = 32; o > 0; o >>= 1) {
      dsum += __shfl_down(dsum, o, 64);
      p0 += __shfl_down(p0, o, 64); p1 += __shfl_down(p1, o, 64);
      p2 += __shfl_down(p2, o, 64); p3 += __shfl_down(p3, o, 64);
    }
    if (lane == 0) { wred[wv][0] = dsum; wred[wv][1] = p0; wred[wv][2] = p1; wred[wv][3] = p2; wred[wv][4] = p3; }
    __syncthreads();
    if (threadIdx.x == 0) {
      float d = 0.f, q0 = 0.f, q1 = 0.f, q2 = 0.f, q3 = 0.f;
      for (int w = 0; w < 4; w++) { d += wred[w][0]; q0 += wred[w][1]; q1 += wred[w][2]; q2 += wred[w][3]; q3 += wred[w][4]; }
      ccv[0] = vv / q0; ccv[1] = vv / q1; ccv[2] = vv / q2; ccv[3] = vv / q3;
      s_err = d / (float)NN;
    }
    __syncthreads();
    if (s_err < 0.01f) break;               // uniform
  }
  float w0 = wts[0], w1 = wts[1], w2 = wts[2], w3 = wts[3];
  float cc0 = ccv[0], cc1 = ccv[1], cc2 = ccv[2], cc3 = ccv[3];
  float bsum = 0.f; int nanloc = 0;
  const int* gtb = gt + b * NN;
  for (int n = threadIdx.x; n < NN; n += 256) {
    float4 kv = Ks[n];
    float rv = r[n];
    float T0 = rv * cc0 * kv.x, T1 = rv * cc1 * kv.y, T2 = rv * cc2 * kv.z, T3 = rv * cc3 * kv.w;
    if (T0 != T0 || T1 != T1 || T2 != T2 || T3 != T3) nanloc = 1;
    float pred = T0 * w0 + T1 * w1 + T2 * w2 + T3 * w3;
    float p = fminf(fmaxf(pred, 0.f), 1.f);
    float t = (gtb[n] == c + 1) ? fmaxf(logf(p), -100.f) : fmaxf(logf(1.f - p), -100.f);
    bsum += t;
  }
  if (nanloc) s_nan = 1;
  for (int o = 32; o > 0; o >>= 1) bsum += __shfl_down(bsum, o, 64);
  if (lane == 0) wred[wv][0] = bsum;
  __syncthreads();
  if (threadIdx.x == 0) {
    float tot = wred[0][0] + wred[1][0] + wred[2][0] + wred[3][0];
    if (s_nan) { bce[bc] = 0.f; vld[bc] = 0; }
    else { bce[bc] = -(tot / (float)NN); vld[bc] = 1; }
  }
}

// ---------- final scalar: sum(bce)/(num_valid + 1e-4) ----------
__global__ void k_final(const float* __restrict__ bce, const int* __restrict__ vld,
                        float* __restrict__ out) {
  __shared__ float rs[256];
  __shared__ float rc[256];
  float s = 0.f, cv = 0.f;
  for (int t = threadIdx.x; t < BB * CC; t += 256) { s += bce[t]; cv += (float)vld[t]; }
  rs[threadIdx.x] = s; rc[threadIdx.x] = cv; __syncthreads();
  for (int o = 128; o > 0; o >>= 1) {
    if (threadIdx.x < o) { rs[threadIdx.x] += rs[threadIdx.x + o]; rc[threadIdx.x] += rc[threadIdx.x + o]; }
    __syncthreads();
  }
  if (threadIdx.x == 0) out[0] = rs[0] / (rc[0] + 0.0001f);
}

extern "C" void kernel_launch(void* const* d_in, const int* in_sizes, int n_in,
                              void* d_out, int out_size, void* d_ws, size_t ws_size,
                              hipStream_t stream) {
  (void)in_sizes; (void)n_in; (void)out_size; (void)ws_size;
  const float* query = (const float*)d_in[0];
  const float* score = (const float*)d_in[1];
  const int*   label = (const int*)d_in[2];
  const int*   gt    = (const int*)d_in[3];
  const float* wts   = (const float*)d_in[4];
  float* ws = (float*)d_ws;

  size_t off = 0;
  int* cls = (int*)(ws + off);       off += (size_t)BB * MM;
  int* cnt = (int*)(ws + off);       off += (size_t)BB * CC;
  float* sm = ws + off;              off += (size_t)BB * MM;
  float* classsum = ws + off;        off += (size_t)BB * CC * DD;
  float* totalsum = ws + off;        off += (size_t)BB * DD;
  float* ph = ws + off;              off += (size_t)BB * CC * KP * DD;
  float* q0h = ws + off;             off += (size_t)NN * DD;
  float* P = ws + off;               off += (size_t)2 * NN * BB * CC * KP;  // 16 MB
  float* Km = ws + off;              off += (size_t)BB * CC * NN * KP;      // 8 MB
  float* bce = ws + off;             off += (size_t)BB * CC;
  int* vld = (int*)(ws + off);       off += (size_t)BB * CC;   // ~41 MB total

  hipMemsetAsync(cnt, 0, (size_t)BB * CC * sizeof(int), stream);
  k_cls<<<(BB * MM + 255) / 256, 256, 0, stream>>>(score, cls, sm, cnt);
  k_kmeans<<<BB * CC, 256, 0, stream>>>(query, cls, sm, cnt, label, ph, classsum);
  k_totalsum<<<(BB * DD) / 256, 256, 0, stream>>>(classsum, totalsum);
  k_backbone<<<BB * CC, 256, 0, stream>>>(totalsum, classsum, cnt, label, ph);
  k_q0h<<<NN, 64, 0, stream>>>(query, q0h);
  dim3 gg((NN + 63) / 64, (BB * CC * KP) / 64, 2);
  k_gemm<<<gg, 256, 0, stream>>>(q0h, ph, P);
  k_kred<<<(NN * BB * CC + 255) / 256, 256, 0, stream>>>(P, Km);
  k_sink<<<BB * CC, 256, 0, stream>>>(Km, label, cnt, gt, wts, bce, vld);
  k_final<<<1, 256, 0, stream>>>(bce, vld, (float*)d_out);
}

// Round 3
// 381.783 us; speedup vs baseline: 2.5406x; 1.0939x over previous
//
#include <hip/hip_runtime.h>
#include <cmath>

#define BB 32     // batch
#define NN 784    // full points (28*28)
#define MM 392    // downsampled points (::2)
#define DD 1024   // feature dim
#define CC 20     // classes
#define JJ 3      // k-means centroids per class (K-1)
#define KP 4      // protos per class (3 centroids + backbone)
#define KM_ITERS 10

// ---------- cls_assign = argmax(score[:, ::2, :]), sm = mean, cnt via int atomics ----------
__global__ void k_cls(const float* __restrict__ score, int* __restrict__ cls,
                      float* __restrict__ sm, int* __restrict__ cnt) {
  int t = blockIdx.x * blockDim.x + threadIdx.x;
  if (t >= BB * MM) return;
  int b = t / MM, i = t - b * MM;
  const float* s = score + ((size_t)b * NN + 2 * i) * CC;
  float best = s[0]; int bi = 0; float acc = s[0];
  #pragma unroll
  for (int c = 1; c < CC; c++) { float v = s[c]; acc += v; if (v > best) { best = v; bi = c; } }
  cls[t] = bi;
  sm[t] = acc / (float)CC;
  atomicAdd(&cnt[b * CC + bi], 1);
}

// ---------- validity compaction: vlist[pos]=bc for valid pairs, cpos[bc], nv ----------
__global__ void k_valid(const int* __restrict__ label, const int* __restrict__ cnt,
                        int* __restrict__ vlist, int* __restrict__ cpos, int* __restrict__ nvp) {
  __shared__ int sf[1024];
  int t = threadIdx.x;
  int flag = 0;
  if (t < BB * CC) flag = (label[t] > 0 && cnt[t] >= KP) ? 1 : 0;
  sf[t] = flag;
  __syncthreads();
  for (int off = 1; off < 1024; off <<= 1) {
    int v = sf[t];
    int add = (t >= off) ? sf[t - off] : 0;
    __syncthreads();
    sf[t] = v + add;
    __syncthreads();
  }
  if (t < BB * CC) {
    int pos = sf[t] - flag;
    cpos[t] = flag ? pos : -1;
    if (flag) vlist[pos] = t;
  }
  if (t == 0) *nvp = sf[BB * CC - 1];
}

// ---------- fused k-means per (b,c); LDS trimmed to ~38.6 KB for 4 blocks/CU ----------
__global__ __launch_bounds__(256) void k_kmeans(
    const float* __restrict__ query, const int* __restrict__ cls,
    const float* __restrict__ sm, const int* __restrict__ cnt,
    const int* __restrict__ label,
    float* __restrict__ ph, float* __restrict__ classsum) {
  int bc = blockIdx.x; int b = bc / CC, c = bc - b * CC;
  int tid = threadIdx.x, lane = tid & 63, wv = tid >> 6;

  __shared__ float s_part[2][JJ][DD];   // 24 KB (ping-pong partials); front aliased as s_cls
  __shared__ int s_list[MM];
  __shared__ float s_cen[JJ][DD];       // 12 KB
  __shared__ int s_kcnt[4][JJ];
  __shared__ float s_smv[4][JJ];
  __shared__ int s_memcnt;
  __shared__ int s_ord[JJ];
  __shared__ float s_red[4][4];
  __shared__ float s_bcast;

  int* s_cls = (int*)&s_part[0][0][0];  // alias; dead after membership build
  for (int i = tid; i < MM; i += 256) s_cls[i] = cls[b * MM + i];
  __syncthreads();
  if (tid == 0) {
    int mc = 0;
    for (int i = 0; i < MM; i++) if (s_cls[i] == c) s_list[mc++] = i;
    s_memcnt = mc;
  }
  __syncthreads();
  int memcnt = s_memcnt;

  // ---- pass A: classsum = sum of member rows (needed for totalsum for ALL bc)
  {
    float4 a0 = make_float4(0.f, 0.f, 0.f, 0.f), a1 = a0, a2 = a0, a3 = a0;
    for (int g = wv; g < memcnt; g += 4) {
      const float* qr = query + ((size_t)b * NN + 2 * s_list[g]) * DD;
      float4 v0 = *(const float4*)(qr + lane * 4);
      float4 v1 = *(const float4*)(qr + lane * 4 + 256);
      float4 v2 = *(const float4*)(qr + lane * 4 + 512);
      float4 v3 = *(const float4*)(qr + lane * 4 + 768);
      a0.x += v0.x; a0.y += v0.y; a0.z += v0.z; a0.w += v0.w;
      a1.x += v1.x; a1.y += v1.y; a1.z += v1.z; a1.w += v1.w;
      a2.x += v2.x; a2.y += v2.y; a2.z += v2.z; a2.w += v2.w;
      a3.x += v3.x; a3.y += v3.y; a3.z += v3.z; a3.w += v3.w;
    }
    if (wv < 2) {
      *(float4*)&s_part[wv][0][lane * 4]       = a0;
      *(float4*)&s_part[wv][0][lane * 4 + 256] = a1;
      *(float4*)&s_part[wv][0][lane * 4 + 512] = a2;
      *(float4*)&s_part[wv][0][lane * 4 + 768] = a3;
    }
    __syncthreads();
    if (wv >= 2) {
      int w = wv - 2;
      float4 t0 = *(const float4*)&s_part[w][0][lane * 4];
      float4 t1 = *(const float4*)&s_part[w][0][lane * 4 + 256];
      float4 t2 = *(const float4*)&s_part[w][0][lane * 4 + 512];
      float4 t3 = *(const float4*)&s_part[w][0][lane * 4 + 768];
      a0.x += t0.x; a0.y += t0.y; a0.z += t0.z; a0.w += t0.w;
      a1.x += t1.x; a1.y += t1.y; a1.z += t1.z; a1.w += t1.w;
      a2.x += t2.x; a2.y += t2.y; a2.z += t2.z; a2.w += t2.w;
      a3.x += t3.x; a3.y += t3.y; a3.z += t3.z; a3.w += t3.w;
      *(float4*)&s_part[w][0][lane * 4]       = a0;
      *(float4*)&s_part[w][0][lane * 4 + 256] = a1;
      *(float4*)&s_part[w][0][lane * 4 + 512] = a2;
      *(float4*)&s_part[w][0][lane * 4 + 768] = a3;
    }
    __syncthreads();
    for (int k = tid; k < DD; k += 256)
      classsum[(size_t)bc * DD + k] = s_part[0][0][k] + s_part[1][0][k];
  }

  if (label[bc] <= 0 || memcnt < KP) return;   // invalid: protos never consumed

  // ---- init centroids = first JJ members; compute initial cen2
  float c2_0, c2_1, c2_2;
  {
    float pp[JJ];
    for (int j = 0; j < JJ; j++) {
      const float* qr = query + ((size_t)b * NN + 2 * s_list[j]) * DD;
      float4 v = *(const float4*)(qr + tid * 4);
      *(float4*)&s_cen[j][tid * 4] = v;
      pp[j] = v.x * v.x + v.y * v.y + v.z * v.z + v.w * v.w;
    }
    for (int o = 1; o < 64; o <<= 1) {
      pp[0] += __shfl_xor(pp[0], o, 64);
      pp[1] += __shfl_xor(pp[1], o, 64);
      pp[2] += __shfl_xor(pp[2], o, 64);
    }
    if (lane == 0) { s_red[wv][0] = pp[0]; s_red[wv][1] = pp[1]; s_red[wv][2] = pp[2]; }
    __syncthreads();
    c2_0 = s_red[0][0] + s_red[1][0] + s_red[2][0] + s_red[3][0];
    c2_1 = s_red[0][1] + s_red[1][1] + s_red[2][1] + s_red[3][1];
    c2_2 = s_red[0][2] + s_red[1][2] + s_red[2][2] + s_red[3][2];
  }

  for (int it = 0; it < KM_ITERS; it++) {
    // ---- assignment + register accumulation (rows wv::4)
    float4 A0[4], A1[4], A2[4];
    #pragma unroll
    for (int u = 0; u < 4; u++) {
      A0[u] = make_float4(0.f, 0.f, 0.f, 0.f); A1[u] = A0[u]; A2[u] = A0[u];
    }
    int c0 = 0, c1 = 0, c2 = 0;
    int g = wv;
    float4 q[4];
    if (g < memcnt) {
      const float* qr = query + ((size_t)b * NN + 2 * s_list[g]) * DD;
      #pragma unroll
      for (int u = 0; u < 4; u++) q[u] = *(const float4*)(qr + lane * 4 + u * 256);
    }
    while (g < memcnt) {
      int gn = g + 4;
      float4 qn[4];
      if (gn < memcnt) {
        const float* qr = query + ((size_t)b * NN + 2 * s_list[gn]) * DD;
        #pragma unroll
        for (int u = 0; u < 4; u++) qn[u] = *(const float4*)(qr + lane * 4 + u * 256);
      }
      float x2 = 0.f, d0 = 0.f, d1 = 0.f, d2 = 0.f;
      #pragma unroll
      for (int u = 0; u < 4; u++) {
        float4 qv = q[u];
        float4 v0 = *(const float4*)&s_cen[0][lane * 4 + u * 256];
        float4 v1 = *(const float4*)&s_cen[1][lane * 4 + u * 256];
        float4 v2 = *(const float4*)&s_cen[2][lane * 4 + u * 256];
        x2 += qv.x * qv.x + qv.y * qv.y + qv.z * qv.z + qv.w * qv.w;
        d0 += qv.x * v0.x + qv.y * v0.y + qv.z * v0.z + qv.w * v0.w;
        d1 += qv.x * v1.x + qv.y * v1.y + qv.z * v1.z + qv.w * v1.w;
        d2 += qv.x * v2.x + qv.y * v2.y + qv.z * v2.z + qv.w * v2.w;
      }
      for (int o = 1; o < 64; o <<= 1) {
        x2 += __shfl_xor(x2, o, 64); d0 += __shfl_xor(d0, o, 64);
        d1 += __shfl_xor(d1, o, 64); d2 += __shfl_xor(d2, o, 64);
      }
      float e0 = (x2 - 2.f * d0) + c2_0;
      float e1 = (x2 - 2.f * d1) + c2_1;
      float e2 = (x2 - 2.f * d2) + c2_2;
      int bj = 0; float bv = e0;
      if (e1 < bv) { bv = e1; bj = 1; }
      if (e2 < bv) { bv = e2; bj = 2; }
      if (bj == 0) {
        #pragma unroll
        for (int u = 0; u < 4; u++) { A0[u].x += q[u].x; A0[u].y += q[u].y; A0[u].z += q[u].z; A0[u].w += q[u].w; }
        c0++;
      } else if (bj == 1) {
        #pragma unroll
        for (int u = 0; u < 4; u++) { A1[u].x += q[u].x; A1[u].y += q[u].y; A1[u].z += q[u].z; A1[u].w += q[u].w; }
        c1++;
      } else {
        #pragma unroll
        for (int u = 0; u < 4; u++) { A2[u].x += q[u].x; A2[u].y += q[u].y; A2[u].z += q[u].z; A2[u].w += q[u].w; }
        c2++;
      }
      #pragma unroll
      for (int u = 0; u < 4; u++) q[u] = qn[u];
      g = gn;
    }
    if (lane == 0) { s_kcnt[wv][0] = c0; s_kcnt[wv][1] = c1; s_kcnt[wv][2] = c2; }
    // ---- ping-pong cross-wave reduction: buf0 = w0+w2, buf1 = w1+w3
    if (wv < 2) {
      #pragma unroll
      for (int u = 0; u < 4; u++) {
        *(float4*)&s_part[wv][0][lane * 4 + u * 256] = A0[u];
        *(float4*)&s_part[wv][1][lane * 4 + u * 256] = A1[u];
        *(float4*)&s_part[wv][2][lane * 4 + u * 256] = A2[u];
      }
    }
    __syncthreads();
    if (wv >= 2) {
      int w = wv - 2;
      #pragma unroll
      for (int u = 0; u < 4; u++) {
        float4 t0 = *(const float4*)&s_part[w][0][lane * 4 + u * 256];
        float4 t1 = *(const float4*)&s_part[w][1][lane * 4 + u * 256];
        float4 t2 = *(const float4*)&s_part[w][2][lane * 4 + u * 256];
        t0.x += A0[u].x; t0.y += A0[u].y; t0.z += A0[u].z; t0.w += A0[u].w;
        t1.x += A1[u].x; t1.y += A1[u].y; t1.z += A1[u].z; t1.w += A1[u].w;
        t2.x += A2[u].x; t2.y += A2[u].y; t2.z += A2[u].z; t2.w += A2[u].w;
        *(float4*)&s_part[w][0][lane * 4 + u * 256] = t0;
        *(float4*)&s_part[w][1][lane * 4 + u * 256] = t1;
        *(float4*)&s_part[w][2][lane * 4 + u * 256] = t2;
      }
    }
    __syncthreads();
    // ---- update: new centroid + cen2 partials fused (thread tid owns float4 k4=tid of each j)
    int kc0 = s_kcnt[0][0] + s_kcnt[1][0] + s_kcnt[2][0] + s_kcnt[3][0];
    int kc1 = s_kcnt[0][1] + s_kcnt[1][1] + s_kcnt[2][1] + s_kcnt[3][1];
    int kc2 = s_kcnt[0][2] + s_kcnt[1][2] + s_kcnt[2][2] + s_kcnt[3][2];
    float pp[JJ];
    #pragma unroll
    for (int j = 0; j < JJ; j++) {
      int kc = (j == 0) ? kc0 : (j == 1 ? kc1 : kc2);
      float4 nvv;
      if (kc > 0) {
        float4 s0 = *(const float4*)&s_part[0][j][tid * 4];
        float4 s1 = *(const float4*)&s_part[1][j][tid * 4];
        float inv = 1.0f / (float)kc;
        nvv = make_float4((s0.x + s1.x) * inv, (s0.y + s1.y) * inv,
                          (s0.z + s1.z) * inv, (s0.w + s1.w) * inv);
        *(float4*)&s_cen[j][tid * 4] = nvv;
      } else {
        nvv = *(const float4*)&s_cen[j][tid * 4];
      }
      pp[j] = nvv.x * nvv.x + nvv.y * nvv.y + nvv.z * nvv.z + nvv.w * nvv.w;
    }
    for (int o = 1; o < 64; o <<= 1) {
      pp[0] += __shfl_xor(pp[0], o, 64);
      pp[1] += __shfl_xor(pp[1], o, 64);
      pp[2] += __shfl_xor(pp[2], o, 64);
    }
    if (lane == 0) { s_red[wv][0] = pp[0]; s_red[wv][1] = pp[1]; s_red[wv][2] = pp[2]; }
    __syncthreads();
    c2_0 = s_red[0][0] + s_red[1][0] + s_red[2][0] + s_red[3][0];
    c2_1 = s_red[0][1] + s_red[1][1] + s_red[2][1] + s_red[3][1];
    c2_2 = s_red[0][2] + s_red[1][2] + s_red[2][2] + s_red[3][2];
  }

  // ---- final assignment: kcnt + sm-sum only
  {
    int c0 = 0, c1 = 0, c2 = 0;
    float sm0 = 0.f, sm1 = 0.f, sm2 = 0.f;
    for (int g = wv; g < memcnt; g += 4) {
      const float* qr = query + ((size_t)b * NN + 2 * s_list[g]) * DD;
      float x2 = 0.f, d0 = 0.f, d1 = 0.f, d2 = 0.f;
      #pragma unroll
      for (int u = 0; u < 4; u++) {
        float4 qv = *(const float4*)(qr + lane * 4 + u * 256);
        float4 v0 = *(const float4*)&s_cen[0][lane * 4 + u * 256];
        float4 v1 = *(const float4*)&s_cen[1][lane * 4 + u * 256];
        float4 v2 = *(const float4*)&s_cen[2][lane * 4 + u * 256];
        x2 += qv.x * qv.x + qv.y * qv.y + qv.z * qv.z + qv.w * qv.w;
        d0 += qv.x * v0.x + qv.y * v0.y + qv.z * v0.z + qv.w * v0.w;
        d1 += qv.x * v1.x + qv.y * v1.y + qv.z * v1.z + qv.w * v1.w;
        d2 += qv.x * v2.x + qv.y * v2.y + qv.z * v2.z + qv.w * v2.w;
      }
      for (int o = 1; o < 64; o <<= 1) {
        x2 += __shfl_xor(x2, o, 64); d0 += __shfl_xor(d0, o, 64);
        d1 += __shfl_xor(d1, o, 64); d2 += __shfl_xor(d2, o, 64);
      }
      float e0 = (x2 - 2.f * d0) + c2_0;
      float e1 = (x2 - 2.f * d1) + c2_1;
      float e2 = (x2 - 2.f * d2) + c2_2;
      int bj = 0; float bv = e0;
      if (e1 < bv) { bv = e1; bj = 1; }
      if (e2 < bv) { bv = e2; bj = 2; }
      float sv = sm[b * MM + s_list[g]];
      if (bj == 0) { c0++; sm0 += sv; }
      else if (bj == 1) { c1++; sm1 += sv; }
      else { c2++; sm2 += sv; }
    }
    if (lane == 0) {
      s_kcnt[wv][0] = c0; s_kcnt[wv][1] = c1; s_kcnt[wv][2] = c2;
      s_smv[wv][0] = sm0; s_smv[wv][1] = sm1; s_smv[wv][2] = sm2;
    }
  }
  __syncthreads();
  if (tid == 0) {
    float avg[JJ];
    for (int j = 0; j < JJ; j++) {
      int kc = s_kcnt[0][j] + s_kcnt[1][j] + s_kcnt[2][j] + s_kcnt[3][j];
      float ss = s_smv[0][j] + s_smv[1][j] + s_smv[2][j] + s_smv[3][j];
      avg[j] = (kc > 0) ? (ss / (float)kc) : -INFINITY;
    }
    bool used[JJ] = {false, false, false};
    for (int s = 0; s < JJ; s++) {       // stable argsort descending
      int bi = -1; float bv = 0.f;
      for (int j = 0; j < JJ; j++)
        if (!used[j] && (bi < 0 || avg[j] > bv)) { bi = j; bv = avg[j]; }
      used[bi] = true; s_ord[s] = bi;
    }
  }
  __syncthreads();
  // ---- normalize + write sorted centroids to ph
  for (int jj = 0; jj < JJ; jj++) {
    int j = s_ord[jj];
    float4 v = *(const float4*)&s_cen[j][tid * 4];
    float pp = v.x * v.x + v.y * v.y + v.z * v.z + v.w * v.w;
    for (int o = 1; o < 64; o <<= 1) pp += __shfl_xor(pp, o, 64);
    if (lane == 0) s_red[wv][0] = pp;
    __syncthreads();
    if (tid == 0)
      s_bcast = fmaxf(sqrtf(s_red[0][0] + s_red[1][0] + s_red[2][0] + s_red[3][0]), 1e-12f);
    __syncthreads();
    float nrm = s_bcast;
    float4 o4 = make_float4(v.x / nrm, v.y / nrm, v.z / nrm, v.w / nrm);
    *(float4*)(ph + ((size_t)bc * KP + jj) * DD + tid * 4) = o4;
    __syncthreads();
  }
}

// ---------- totalsum[b][k] = sum_c classsum[b][c][k] ----------
__global__ void k_totalsum(const float* __restrict__ classsum, float* __restrict__ totalsum) {
  int t = blockIdx.x * 256 + threadIdx.x;   // over BB*DD
  int b = t >> 10, k = t & (DD - 1);
  float s = 0.f;
  for (int c = 0; c < CC; c++) s += classsum[((size_t)b * CC + c) * DD + k];
  totalsum[t] = s;
}

// ---------- backbone proto (row 3 of ph), valid bc only ----------
__global__ __launch_bounds__(256) void k_backbone(const float* __restrict__ totalsum,
    const float* __restrict__ classsum, const int* __restrict__ cnt,
    const int* __restrict__ label, float* __restrict__ ph) {
  int bc = blockIdx.x; int b = bc / CC;
  if (label[bc] <= 0 || cnt[bc] < KP) return;
  int tid = threadIdx.x, lane = tid & 63, wv = tid >> 6;
  __shared__ float s_red[4];
  __shared__ float s_nrm;
  float denom = fmaxf((float)(MM - cnt[bc]), 1.f);
  float4 tv = *(const float4*)(totalsum + (size_t)b * DD + tid * 4);
  float4 cv = *(const float4*)(classsum + (size_t)bc * DD + tid * 4);
  float4 v = make_float4((tv.x - cv.x) / denom, (tv.y - cv.y) / denom,
                         (tv.z - cv.z) / denom, (tv.w - cv.w) / denom);
  float pp = v.x * v.x + v.y * v.y + v.z * v.z + v.w * v.w;
  for (int o = 1; o < 64; o <<= 1) pp += __shfl_xor(pp, o, 64);
  if (lane == 0) s_red[wv] = pp;
  __syncthreads();
  if (tid == 0) s_nrm = fmaxf(sqrtf(s_red[0] + s_red[1] + s_red[2] + s_red[3]), 1e-12f);
  __syncthreads();
  float nrm = s_nrm;
  *(float4*)(ph + ((size_t)bc * KP + 3) * DD + tid * 4) =
      make_float4(v.x / nrm, v.y / nrm, v.z / nrm, v.w / nrm);
}

// ---------- q0h = normalize(query[0]) rows; one wave per row ----------
__global__ void k_q0h(const float* __restrict__ query, float* __restrict__ q0h) {
  int n = blockIdx.x;
  const float* src = query + (size_t)n * DD;
  float ss = 0.f;
  for (int k = threadIdx.x; k < DD; k += 64) { float v = src[k]; ss += v * v; }
  for (int o = 32; o > 0; o >>= 1) ss += __shfl_xor(ss, o, 64);
  float nrm = fmaxf(sqrtf(ss), 1e-12f);
  for (int k = threadIdx.x; k < DD; k += 64) q0h[(size_t)n * DD + k] = src[k] / nrm;
}

// ---------- sim GEMM over COMPACTED valid columns, split-K x2 ----------
__global__ __launch_bounds__(256) void k_gemm(const float* __restrict__ A,
    const float* __restrict__ ph, const int* __restrict__ vlist,
    const int* __restrict__ nvp, float* __restrict__ P) {
  int nv4 = 4 * *nvp;
  int n0 = blockIdx.y * 64;
  if (n0 >= nv4) return;                 // uniform early-exit: invalid tail
  __shared__ float As[64][20];
  __shared__ float Bs[64][20];
  int tx = threadIdx.x & 15, ty = threadIdx.x >> 4;
  int m0 = blockIdx.x * 64;
  int s = blockIdx.z;
  int lrow = threadIdx.x >> 2;
  int lk = (threadIdx.x & 3) * 4;
  int brow = n0 + lrow;
  bool bval = brow < nv4;
  const float* Brow = ph;
  if (bval) {
    int bcc = brow >> 2;
    Brow = ph + ((size_t)vlist[bcc] * KP + (brow & 3)) * DD;
  }
  float acc[4][4] = {};
  int kbase = s * 512;
  for (int k0 = kbase; k0 < kbase + 512; k0 += 16) {
    int ar = m0 + lrow;
    float4 av = (ar < NN) ? *(const float4*)(A + (size_t)ar * DD + k0 + lk)
                          : make_float4(0.f, 0.f, 0.f, 0.f);
    *(float4*)&As[lrow][lk] = av;
    float4 bv = bval ? *(const float4*)(Brow + k0 + lk)
                     : make_float4(0.f, 0.f, 0.f, 0.f);
    *(float4*)&Bs[lrow][lk] = bv;
    __syncthreads();
    #pragma unroll
    for (int kk = 0; kk < 16; kk += 4) {
      float4 a4[4], b4[4];
      #pragma unroll
      for (int i = 0; i < 4; i++) a4[i] = *(const float4*)&As[ty * 4 + i][kk];
      #pragma unroll
      for (int j = 0; j < 4; j++) b4[j] = *(const float4*)&Bs[tx + 16 * j][kk];
      #pragma unroll
      for (int i = 0; i < 4; i++)
        #pragma unroll
        for (int j = 0; j < 4; j++) {
          acc[i][j] += a4[i].x * b4[j].x;
          acc[i][j] += a4[i].y * b4[j].y;
          acc[i][j] += a4[i].z * b4[j].z;
          acc[i][j] += a4[i].w * b4[j].w;
        }
    }
    __syncthreads();
  }
  #pragma unroll
  for (int i = 0; i < 4; i++) {
    int mr = m0 + ty * 4 + i;
    if (mr >= NN) continue;
    float* row = P + ((size_t)s * NN + mr) * (size_t)(BB * CC * KP) + n0 + tx;
    #pragma unroll
    for (int j = 0; j < 4; j++) row[16 * j] = acc[i][j];
  }
}

// ---------- reduce split-K + exp -> compact Km[bcc][n][4]; one block per m ----------
__global__ void k_kred(const float* __restrict__ P, const int* __restrict__ nvp,
                       float* __restrict__ Km) {
  int nv = *nvp;
  int m = blockIdx.x;
  const float4* p0 = (const float4*)(P + (size_t)m * (BB * CC * KP));
  const float4* p1 = (const float4*)(P + ((size_t)NN + m) * (BB * CC * KP));
  for (int bcc = threadIdx.x; bcc < nv; bcc += 256) {
    float4 a = p0[bcc], bvv = p1[bcc];
    float4 o;
    o.x = expf(-(1.0f - (a.x + bvv.x)) / 0.1f);
    o.y = expf(-(1.0f - (a.y + bvv.y)) / 0.1f);
    o.z = expf(-(1.0f - (a.z + bvv.z)) / 0.1f);
    o.w = expf(-(1.0f - (a.w + bvv.w)) / 0.1f);
    *((float4*)Km + (size_t)bcc * NN + m) = o;
  }
}

// ---------- Sinkhorn + BCE per (b,c); Km tile resident in LDS ----------
__global__ __launch_bounds__(256) void k_sink(const float* __restrict__ Km,
    const int* __restrict__ label, const int* __restrict__ cnt,
    const int* __restrict__ cpos,
    const int* __restrict__ gt, const float* __restrict__ wts,
    float* __restrict__ bce, int* __restrict__ vld) {
  int bc = blockIdx.x; int b = bc / CC, c = bc - b * CC;
  if (label[bc] <= 0 || cnt[bc] < KP) {     // uniform early-out: invalid pair
    if (threadIdx.x == 0) { bce[bc] = 0.f; vld[bc] = 0; }
    return;
  }
  __shared__ __align__(16) float4 Ks[NN];   // 12.5 KB
  __shared__ float r[NN];
  __shared__ float ccv[KP];
  __shared__ float wred[4][5];
  __shared__ float s_err;
  __shared__ int s_nan;
  const float4* Kg = (const float4*)Km + (size_t)cpos[bc] * NN;
  for (int t = threadIdx.x; t < NN; t += 256) { Ks[t] = Kg[t]; r[t] = 1.f; }
  if (threadIdx.x < KP) ccv[threadIdx.x] = 1.f;
  if (threadIdx.x == 0) s_nan = 0;
  __syncthreads();
  const float uu = 1.0f / (float)NN, vv = 1.0f / (float)KP;
  int lane = threadIdx.x & 63, wv = threadIdx.x >> 6;
  for (int it = 0; it < 100; it++) {
    float c0 = ccv[0], c1 = ccv[1], c2 = ccv[2], c3 = ccv[3];
    float dsum = 0.f, p0 = 0.f, p1 = 0.f, p2 = 0.f, p3 = 0.f;
    for (int n = threadIdx.x; n < NN; n += 256) {
      float4 kv = Ks[n];
      float S = kv.x * c0 + kv.y * c1 + kv.z * c2 + kv.w * c3;
      float r1 = uu / S;
      dsum += fabsf(r1 - r[n]);
      r[n] = r1;
      p0 += kv.x * r1; p1 += kv.y * r1; p2 += kv.z * r1; p3 += kv.w * r1;
    }
    for (int o = 32; o > 0; o >>= 1) {
      dsum += __shfl_down(dsum, o, 64);
      p0 += __shfl_down(p0, o, 64); p1 += __shfl_down(p1, o, 64);
      p2 += __shfl_down(p2, o, 64); p3 += __shfl_down(p3, o, 64);
    }
    if (lane == 0) { wred[wv][0] = dsum; wred[wv][1] = p0; wred[wv][2] = p1; wred[wv][3] = p2; wred[wv][4] = p3; }
    __syncthreads();
    if (threadIdx.x == 0) {
      float d = 0.f, q0 = 0.f, q1 = 0.f, q2 = 0.f, q3 = 0.f;
      for (int w = 0; w < 4; w++) { d += wred[w][0]; q0 += wred[w][1]; q1 += wred[w][2]; q2 += wred[w][3]; q3 += wred[w][4]; }
      ccv[0] = vv / q0; ccv[1] = vv / q1; ccv[2] = vv / q2; ccv[3] = vv / q3;
      s_err = d / (float)NN;
    }
    __syncthreads();
    if (s_err < 0.01f) break;               // uniform
  }
  float w0 = wts[0], w1 = wts[1], w2 = wts[2], w3 = wts[3];
  float cc0 = ccv[0], cc1 = ccv[1], cc2 = ccv[2], cc3 = ccv[3];
  float bsum = 0.f; int nanloc = 0;
  const int* gtb = gt + b * NN;
  for (int n = threadIdx.x; n < NN; n += 256) {
    float4 kv = Ks[n];
    float rv = r[n];
    float T0 = rv * cc0 * kv.x, T1 = rv * cc1 * kv.y, T2 = rv * cc2 * kv.z, T3 = rv * cc3 * kv.w;
    if (T0 != T0 || T1 != T1 || T2 != T2 || T3 != T3) nanloc = 1;
    float pred = T0 * w0 + T1 * w1 + T2 * w2 + T3 * w3;
    float p = fminf(fmaxf(pred, 0.f), 1.f);
    float t = (gtb[n] == c + 1) ? fmaxf(logf(p), -100.f) : fmaxf(logf(1.f - p), -100.f);
    bsum += t;
  }
  if (nanloc) s_nan = 1;
  for (int o = 32; o > 0; o >>= 1) bsum += __shfl_down(bsum, o, 64);
  if (lane == 0) wred[wv][0] = bsum;
  __syncthreads();
  if (threadIdx.x == 0) {
    float tot = wred[0][0] + wred[1][0] + wred[2][0] + wred[3][0];
    if (s_nan) { bce[bc] = 0.f; vld[bc] = 0; }
    else { bce[bc] = -(tot / (float)NN); vld[bc] = 1; }
  }
}

// ---------- final scalar: sum(bce)/(num_valid + 1e-4) ----------
__global__ void k_final(const float* __restrict__ bce, const int* __restrict__ vld,
                        float* __restrict__ out) {
  __shared__ float rs[256];
  __shared__ float rc[256];
  float s = 0.f, cv = 0.f;
  for (int t = threadIdx.x; t < BB * CC; t += 256) { s += bce[t]; cv += (float)vld[t]; }
  rs[threadIdx.x] = s; rc[threadIdx.x] = cv; __syncthreads();
  for (int o = 128; o > 0; o >>= 1) {
    if (threadIdx.x < o) { rs[threadIdx.x] += rs[threadIdx.x + o]; rc[threadIdx.x] += rc[threadIdx.x + o]; }
    __syncthreads();
  }
  if (threadIdx.x == 0) out[0] = rs[0] / (rc[0] + 0.0001f);
}

extern "C" void kernel_launch(void* const* d_in, const int* in_sizes, int n_in,
                              void* d_out, int out_size, void* d_ws, size_t ws_size,
                              hipStream_t stream) {
  (void)in_sizes; (void)n_in; (void)out_size; (void)ws_size;
  const float* query = (const float*)d_in[0];
  const float* score = (const float*)d_in[1];
  const int*   label = (const int*)d_in[2];
  const int*   gt    = (const int*)d_in[3];
  const float* wts   = (const float*)d_in[4];
  float* ws = (float*)d_ws;

  size_t off = 0;
  int* cls = (int*)(ws + off);       off += (size_t)BB * MM;
  int* cnt = (int*)(ws + off);       off += (size_t)BB * CC;
  float* sm = ws + off;              off += (size_t)BB * MM;
  int* vlist = (int*)(ws + off);     off += (size_t)BB * CC;
  int* cpos = (int*)(ws + off);      off += (size_t)BB * CC;
  int* nvp = (int*)(ws + off);       off += 16;
  float* classsum = ws + off;        off += (size_t)BB * CC * DD;
  float* totalsum = ws + off;        off += (size_t)BB * DD;
  float* ph = ws + off;              off += (size_t)BB * CC * KP * DD;
  float* q0h = ws + off;             off += (size_t)NN * DD;
  float* P = ws + off;               off += (size_t)2 * NN * BB * CC * KP;  // 16 MB
  float* Km = ws + off;              off += (size_t)BB * CC * NN * KP;      // 8 MB
  float* bce = ws + off;             off += (size_t)BB * CC;
  int* vld = (int*)(ws + off);       off += (size_t)BB * CC;   // ~41 MB total

  hipMemsetAsync(cnt, 0, (size_t)BB * CC * sizeof(int), stream);
  k_cls<<<(BB * MM + 255) / 256, 256, 0, stream>>>(score, cls, sm, cnt);
  k_valid<<<1, 1024, 0, stream>>>(label, cnt, vlist, cpos, nvp);
  k_kmeans<<<BB * CC, 256, 0, stream>>>(query, cls, sm, cnt, label, ph, classsum);
  k_totalsum<<<(BB * DD) / 256, 256, 0, stream>>>(classsum, totalsum);
  k_backbone<<<BB * CC, 256, 0, stream>>>(totalsum, classsum, cnt, label, ph);
  k_q0h<<<NN, 64, 0, stream>>>(query, q0h);
  dim3 gg((NN + 63) / 64, (BB * CC * KP) / 64, 2);
  k_gemm<<<gg, 256, 0, stream>>>(q0h, ph, vlist, nvp, P);
  k_kred<<<NN, 256, 0, stream>>>(P, nvp, Km);
  k_sink<<<BB * CC, 256, 0, stream>>>(Km, label, cnt, cpos, gt, wts, bce, vld);
  k_final<<<1, 256, 0, stream>>>(bce, vld, (float*)d_out);
}